// Round 2
// baseline (2412.884 us; speedup 1.0000x reference)
//
#include <hip/hip_runtime.h>
#include <math.h>

#define T_DIM 4096
#define D_DIM 1024
#define NUM_PAT 8
#define PAT_LEN 128
#define HALF_PAT 64
#define CHUNK_B 4          // batches per pipeline chunk (64 MB of x)

typedef __attribute__((ext_vector_type(4))) float f4;

struct BatchParams {
    float mean;
    float inv;
    int lo[NUM_PAT];
    int hi[NUM_PAT];
    int pad[14];   // pad to 128 B
};

// ---------------------------------------------------------------------------
// (v,i) total order matching jax.lax.top_k: value descending, ties -> lower
// index wins. All elements have distinct i, so this is a strict total order.
// ---------------------------------------------------------------------------
__device__ __forceinline__ bool better(float va, int ia, float vb, int ib) {
    return (va > vb) || (va == vb && ia < ib);
}

// ---------------------------------------------------------------------------
// Zero the per-batch completion counters (workspace is poisoned every
// iteration). Counters are padded to 64 B stride so the 4 concurrently-hot
// counters of a chunk live on distinct cache lines.
// ---------------------------------------------------------------------------
__global__ void zero_counters(int* __restrict__ cnt, int n) {
    for (int i = threadIdx.x; i < n; i += blockDim.x) cnt[i] = 0;
}

// ---------------------------------------------------------------------------
// Fused kernel: per-row sum/sumsq reduce (one wave per row, 4 rows/block)
// + last-block-per-batch inline select.
//
//  Reduce: fp64 row sum + sumsq over D=1024 via float4 loads, wave shuffle.
//  Publication: plain rowsum stores -> __threadfence() (agent release) ->
//  per-batch AGENT-scope ACQ_REL atomicAdd. The block that completes its
//  batch (old == 1023) acquires (fence invalidates L1/L2 so other XCDs'
//  rowsum writes are visible) and runs the select for that batch:
//   - xt from rowsum, 3-window local-peak mask (-inf borders)
//   - per-thread sorted top-8 over 16 stride-256 candidates, then an
//     8-level bitonic merge tree in LDS (half-cleaner + dist 4/2/1 clean);
//     tie-break identical to jax.lax.top_k
//   - window-gathered mean / unbiased std from rowsum/rowsumsq (fp64)
// ---------------------------------------------------------------------------
__global__ __launch_bounds__(256) void reduce_select_kernel(
        const float* __restrict__ x,
        double* __restrict__ rowsum,
        double* __restrict__ rowsumsq,
        BatchParams* __restrict__ params,
        int* __restrict__ cnt,
        int base_row) {
    int lrow = (int)(blockIdx.x << 2) + (int)(threadIdx.x >> 6);
    int row  = base_row + lrow;          // 4 rows/block, all in one batch
    int lane = threadIdx.x & 63;
    int j    = threadIdx.x;
    int batch = row >> 12;               // T_DIM = 4096 rows per batch

    __shared__ float xs[T_DIM];
    __shared__ float sv[256 * 8];
    __shared__ int   si[256 * 8];
    __shared__ int   ind[NUM_PAT];
    __shared__ double w1[4], w2[4];
    __shared__ int    is_last;

    // --- phase 1: row reduce ---------------------------------------------
    {
        const float4* xp = (const float4*)(x + (size_t)row * D_DIM);
        float4 v[4];
#pragma unroll
        for (int q = 0; q < 4; ++q) v[q] = xp[lane + q * 64];
        double s1 = 0.0, s2 = 0.0;
#pragma unroll
        for (int q = 0; q < 4; ++q) {
            double a = (double)v[q].x, b2 = (double)v[q].y;
            double c = (double)v[q].z, d = (double)v[q].w;
            s1 += (a + b2) + (c + d);
            s2 += (a * a + b2 * b2) + (c * c + d * d);
        }
#pragma unroll
        for (int off = 32; off >= 1; off >>= 1) {
            s1 += __shfl_down(s1, off, 64);
            s2 += __shfl_down(s2, off, 64);
        }
        if (lane == 0) {
            rowsum[row]   = s1;
            rowsumsq[row] = s2;
        }
    }

    // --- publish + last-block election -----------------------------------
    __threadfence();                     // agent-scope release of rowsum stores
    __syncthreads();
    if (j == 0) {
        int old = __hip_atomic_fetch_add(&cnt[batch << 4], 1,
                                         __ATOMIC_ACQ_REL,
                                         __HIP_MEMORY_SCOPE_AGENT);
        is_last = (old == (T_DIM / 4) - 1);
    }
    __syncthreads();
    if (!is_last) return;
    __threadfence();                     // agent-scope acquire: see all rowsums

    // --- phase 2: select for this batch -----------------------------------
    int b = batch;
    const double* rs = rowsum   + (size_t)b * T_DIM;
    const double* rq = rowsumsq + (size_t)b * T_DIM;

    for (int t = j; t < T_DIM; t += 256) xs[t] = (float)rs[t];
    __syncthreads();

    // per-thread sorted top-8 over 16 stride-256 candidates
    float lv[8]; int li[8];
#pragma unroll
    for (int q = 0; q < 8; ++q) { lv[q] = -INFINITY; li[q] = 0x7fffffff; }
#pragma unroll
    for (int q = 0; q < 16; ++q) {
        int t = j + q * 256;
        float c = xs[t];
        float l = (t > 0)         ? xs[t - 1] : -INFINITY;
        float r = (t < T_DIM - 1) ? xs[t + 1] : -INFINITY;
        float v = (c >= l && c >= r) ? c : 0.0f;   // local peak else 0
        if (better(v, t, lv[7], li[7])) {
            lv[7] = v; li[7] = t;
#pragma unroll
            for (int p = 7; p > 0; --p) {
                if (better(lv[p], li[p], lv[p - 1], li[p - 1])) {
                    float tv = lv[p]; lv[p] = lv[p - 1]; lv[p - 1] = tv;
                    int   ti = li[p]; li[p] = li[p - 1]; li[p - 1] = ti;
                }
            }
        }
    }

    // merge tree: 256 sorted lists -> 1
#pragma unroll
    for (int q = 0; q < 8; ++q) { sv[(j << 3) + q] = lv[q]; si[(j << 3) + q] = li[q]; }
    __syncthreads();
    for (int s = 128; s >= 1; s >>= 1) {
        if (j < s) {
            float ov[8]; int oi[8];
#pragma unroll
            for (int q = 0; q < 8; ++q) {
                ov[q] = sv[((j + s) << 3) + q];
                oi[q] = si[((j + s) << 3) + q];
            }
            float mv[8]; int mi[8];
#pragma unroll
            for (int q = 0; q < 8; ++q) {     // half-cleaner: top-8 of union
                if (better(lv[q], li[q], ov[7 - q], oi[7 - q])) {
                    mv[q] = lv[q]; mi[q] = li[q];
                } else {
                    mv[q] = ov[7 - q]; mi[q] = oi[7 - q];
                }
            }
#define CE(a, b_) { if (better(mv[b_], mi[b_], mv[a], mi[a])) { \
                float tv = mv[a]; mv[a] = mv[b_]; mv[b_] = tv;  \
                int   ti = mi[a]; mi[a] = mi[b_]; mi[b_] = ti; } }
            CE(0, 4) CE(1, 5) CE(2, 6) CE(3, 7)   // bitonic clean: dist 4
            CE(0, 2) CE(1, 3) CE(4, 6) CE(5, 7)   // dist 2
            CE(0, 1) CE(2, 3) CE(4, 5) CE(6, 7)   // dist 1
#undef CE
#pragma unroll
            for (int q = 0; q < 8; ++q) {
                lv[q] = mv[q]; li[q] = mi[q];
                sv[(j << 3) + q] = mv[q]; si[(j << 3) + q] = mi[q];
            }
        }
        __syncthreads();
    }
    if (j == 0) {
#pragma unroll
        for (int k = 0; k < NUM_PAT; ++k) ind[k] = li[k];
    }
    __syncthreads();

    // gather-window sums over M = 8*128 (clipped, possibly dup) rows
    double s1 = 0.0, s2 = 0.0;
#pragma unroll
    for (int mq = 0; mq < 4; ++mq) {
        int m = j + mq * 256;
        int k = m >> 7;
        int t = ind[k] + (m & (PAT_LEN - 1)) - HALF_PAT;
        t = min(max(t, 0), T_DIM - 1);
        s1 += rs[t];
        s2 += rq[t];
    }
#pragma unroll
    for (int off = 32; off >= 1; off >>= 1) {
        s1 += __shfl_down(s1, off, 64);
        s2 += __shfl_down(s2, off, 64);
    }
    if ((j & 63) == 0) { w1[j >> 6] = s1; w2[j >> 6] = s2; }
    __syncthreads();
    if (j == 0) {
        double S1 = (w1[0] + w1[1]) + (w1[2] + w1[3]);
        double S2 = (w2[0] + w2[1]) + (w2[2] + w2[3]);
        const double N = (double)(NUM_PAT * PAT_LEN) * (double)D_DIM;
        double mean = S1 / N;
        double var  = (S2 - S1 * S1 / N) / (N - 1.0);
        if (var < 0.0) var = 0.0;
        float stdf = (float)sqrt(var);
        params[b].mean = (float)mean;
        params[b].inv  = 1.0f / (stdf + 1e-8f);
#pragma unroll
        for (int k = 0; k < NUM_PAT; ++k) {
            params[b].lo[k] = max(0, ind[k] - HALF_PAT);
            params[b].hi[k] = min(T_DIM - 1, ind[k] + HALF_PAT - 1);
        }
    }
}

// ---------------------------------------------------------------------------
// Apply kernel (per chunk). 4 rows per 256-thread block, one wave per row
// (mask & params wave-uniform -> zero divergence). The chunk's 64 MB of x
// was just read by reduce_select_kernel -> L3-resident -> reads hit L3 and
// the kernel is write-bound. Non-temporal stores keep `out` from competing
// for L3 (out is never re-read).
// ---------------------------------------------------------------------------
__global__ __launch_bounds__(256) void apply_kernel(
        const float* __restrict__ x,
        const float* __restrict__ gamma,
        const float* __restrict__ beta,
        const BatchParams* __restrict__ params,
        float* __restrict__ out,
        int base_row) {
    int row  = base_row + (int)(blockIdx.x << 2) + (int)(threadIdx.x >> 6);
    int lane = threadIdx.x & 63;
    int b = row >> 12;                                  // T = 4096 rows/batch
    int t = row & (T_DIM - 1);
    const BatchParams* P = params + b;
    bool covered = false;
#pragma unroll
    for (int k = 0; k < NUM_PAT; ++k)
        covered |= (t >= P->lo[k] && t <= P->hi[k]);
    float mask = covered ? (float)0.8807970779778823 : (float)0.04742587317756678;
    float mean = P->mean;
    float inv  = P->inv;

    size_t base = (size_t)row * D_DIM;
    const float4* xp = (const float4*)(x + base);
    float4*       op = (float4*)(out + base);
    const float4* gp = (const float4*)gamma;
    const float4* bp = (const float4*)beta;

    float4 xv[4], g[4], bt[4];
#pragma unroll
    for (int q = 0; q < 4; ++q) {
        int c4 = lane + q * 64;
        xv[q] = xp[c4];
        g[q]  = gp[c4];
        bt[q] = bp[c4];
    }
#pragma unroll
    for (int q = 0; q < 4; ++q) {
        f4 o;
        o.x = (g[q].x * ((xv[q].x - mean) * inv) + bt[q].x) * mask;
        o.y = (g[q].y * ((xv[q].y - mean) * inv) + bt[q].y) * mask;
        o.z = (g[q].z * ((xv[q].z - mean) * inv) + bt[q].z) * mask;
        o.w = (g[q].w * ((xv[q].w - mean) * inv) + bt[q].w) * mask;
        __builtin_nontemporal_store(o, (f4*)(op + lane + q * 64));
    }
}

// ---------------------------------------------------------------------------
extern "C" void kernel_launch(void* const* d_in, const int* in_sizes, int n_in,
                              void* d_out, int out_size, void* d_ws, size_t ws_size,
                              hipStream_t stream) {
    const float* x     = (const float*)d_in[0];
    const float* gamma = (const float*)d_in[1];
    const float* beta  = (const float*)d_in[2];
    float* out = (float*)d_out;

    int total = in_sizes[0];
    int B = total / (T_DIM * D_DIM);
    int nrows = B * T_DIM;

    double* rowsum   = (double*)d_ws;
    double* rowsumsq = rowsum + nrows;
    BatchParams* params =
        (BatchParams*)((char*)d_ws + 2 * (size_t)nrows * sizeof(double));
    int* cnt = (int*)(params + B);       // B counters, 64 B stride (idx<<4)

    zero_counters<<<1, 256, 0, stream>>>(cnt, B * 16);

    int nchunks = (B + CHUNK_B - 1) / CHUNK_B;
    for (int c = 0; c < nchunks; ++c) {
        int b0 = c * CHUNK_B;
        int nb = (B - b0 < CHUNK_B) ? (B - b0) : CHUNK_B;
        int rows = nb * T_DIM;
        int base_row = b0 * T_DIM;
        reduce_select_kernel<<<rows / 4, 256, 0, stream>>>(
            x, rowsum, rowsumsq, params, cnt, base_row);
        apply_kernel<<<rows / 4, 256, 0, stream>>>(
            x, gamma, beta, params, out, base_row);
    }
}

// Round 3
// 514.379 us; speedup vs baseline: 4.6909x; 4.6909x over previous
//
#include <hip/hip_runtime.h>
#include <math.h>

#define T_DIM 4096
#define D_DIM 1024
#define NUM_PAT 8
#define PAT_LEN 128
#define HALF_PAT 64
#define CHUNK_B 8          // batches per pipeline chunk (128 MB of x << 256 MB L3)

typedef __attribute__((ext_vector_type(4))) float f4;

struct BatchParams {
    float mean;
    float inv;
    int lo[NUM_PAT];
    int hi[NUM_PAT];
    int pad[14];   // pad to 128 B
};

// ---------------------------------------------------------------------------
// Kernel 1: per-row sum and sum-of-squares in fp64. One wave (64 lanes) per
// row of D=1024 floats; 4 waves per 256-thread block. Memory-bound. Normal
// (caching) loads on purpose: pulls the chunk's x into L3 for the apply pass.
// NO device-scope fences anywhere — kernel-boundary coherence (runtime
// release/acquire per dispatch) publishes rowsum to the select kernel.
// ---------------------------------------------------------------------------
__global__ __launch_bounds__(256) void row_reduce_kernel(
        const float* __restrict__ x,
        double* __restrict__ rowsum,
        double* __restrict__ rowsumsq,
        int base_row) {
    int row  = base_row + (int)(blockIdx.x << 2) + (int)(threadIdx.x >> 6);
    int lane = threadIdx.x & 63;
    const float4* xp = (const float4*)(x + (size_t)row * D_DIM);
    float4 v[4];
#pragma unroll
    for (int q = 0; q < 4; ++q) v[q] = xp[lane + q * 64];   // 4 indep loads in flight
    double s1 = 0.0, s2 = 0.0;
#pragma unroll
    for (int q = 0; q < 4; ++q) {
        double a = (double)v[q].x, b = (double)v[q].y;
        double c = (double)v[q].z, d = (double)v[q].w;
        s1 += (a + b) + (c + d);
        s2 += (a * a + b * b) + (c * c + d * d);
    }
#pragma unroll
    for (int off = 32; off >= 1; off >>= 1) {
        s1 += __shfl_down(s1, off, 64);
        s2 += __shfl_down(s2, off, 64);
    }
    if (lane == 0) {
        rowsum[row] = s1;
        rowsumsq[row] = s2;
    }
}

// ---------------------------------------------------------------------------
// (v,i) total order matching jax.lax.top_k: value descending, ties -> lower
// index wins. All elements have distinct i, so this is a strict total order.
// ---------------------------------------------------------------------------
__device__ __forceinline__ bool better(float va, int ia, float vb, int ib) {
    return (va > vb) || (va == vb && ia < ib);
}

// ---------------------------------------------------------------------------
// Kernel 2: one 256-thread block per batch (nb blocks per chunk).
//  - xt (fp32) from rowsum; peak mask (local max over 3-window, -inf borders)
//  - top-8: per-thread sorted top-8 over 16 stride-256 candidates, then an
//    8-level bitonic merge tree in LDS (half-cleaner + dist 4/2/1 clean);
//    tie-break identical to jax.lax.top_k. (Verified in rounds 1-2.)
//  - window-gathered mean / unbiased std via rowsum/rowsumsq (fp64),
//    wave-shuffle reduction.
// ---------------------------------------------------------------------------
__global__ __launch_bounds__(256) void select_kernel(
        const double* __restrict__ rowsum,
        const double* __restrict__ rowsumsq,
        BatchParams* __restrict__ params,
        int b0) {
    int b = b0 + (int)blockIdx.x;
    int j = threadIdx.x;
    __shared__ float xs[T_DIM];
    __shared__ float sv[256 * 8];
    __shared__ int   si[256 * 8];
    __shared__ int   ind[NUM_PAT];
    __shared__ double w1[4], w2[4];

    const double* rs = rowsum   + (size_t)b * T_DIM;
    const double* rq = rowsumsq + (size_t)b * T_DIM;

    for (int t = j; t < T_DIM; t += 256) xs[t] = (float)rs[t];
    __syncthreads();

    // --- per-thread sorted top-8 over 16 stride-256 candidates ------------
    float lv[8]; int li[8];
#pragma unroll
    for (int q = 0; q < 8; ++q) { lv[q] = -INFINITY; li[q] = 0x7fffffff; }
#pragma unroll
    for (int q = 0; q < 16; ++q) {
        int t = j + q * 256;
        float c = xs[t];
        float l = (t > 0)         ? xs[t - 1] : -INFINITY;
        float r = (t < T_DIM - 1) ? xs[t + 1] : -INFINITY;
        float v = (c >= l && c >= r) ? c : 0.0f;   // local peak else 0
        if (better(v, t, lv[7], li[7])) {
            lv[7] = v; li[7] = t;
#pragma unroll
            for (int p = 7; p > 0; --p) {
                if (better(lv[p], li[p], lv[p - 1], li[p - 1])) {
                    float tv = lv[p]; lv[p] = lv[p - 1]; lv[p - 1] = tv;
                    int   ti = li[p]; li[p] = li[p - 1]; li[p - 1] = ti;
                }
            }
        }
    }

    // --- merge tree: 256 sorted lists -> 1 -------------------------------
#pragma unroll
    for (int q = 0; q < 8; ++q) { sv[(j << 3) + q] = lv[q]; si[(j << 3) + q] = li[q]; }
    __syncthreads();
    for (int s = 128; s >= 1; s >>= 1) {
        if (j < s) {
            float ov[8]; int oi[8];
#pragma unroll
            for (int q = 0; q < 8; ++q) {
                ov[q] = sv[((j + s) << 3) + q];
                oi[q] = si[((j + s) << 3) + q];
            }
            float mv[8]; int mi[8];
#pragma unroll
            for (int q = 0; q < 8; ++q) {     // half-cleaner: top-8 of union
                if (better(lv[q], li[q], ov[7 - q], oi[7 - q])) {
                    mv[q] = lv[q]; mi[q] = li[q];
                } else {
                    mv[q] = ov[7 - q]; mi[q] = oi[7 - q];
                }
            }
#define CE(a, b_) { if (better(mv[b_], mi[b_], mv[a], mi[a])) { \
                float tv = mv[a]; mv[a] = mv[b_]; mv[b_] = tv;  \
                int   ti = mi[a]; mi[a] = mi[b_]; mi[b_] = ti; } }
            CE(0, 4) CE(1, 5) CE(2, 6) CE(3, 7)   // bitonic clean: dist 4
            CE(0, 2) CE(1, 3) CE(4, 6) CE(5, 7)   // dist 2
            CE(0, 1) CE(2, 3) CE(4, 5) CE(6, 7)   // dist 1
#undef CE
#pragma unroll
            for (int q = 0; q < 8; ++q) {
                lv[q] = mv[q]; li[q] = mi[q];
                sv[(j << 3) + q] = mv[q]; si[(j << 3) + q] = mi[q];
            }
        }
        __syncthreads();
    }
    if (j == 0) {
#pragma unroll
        for (int k = 0; k < NUM_PAT; ++k) ind[k] = li[k];
    }
    __syncthreads();

    // --- gather-window sums over M = 8*128 (clipped, possibly dup) rows ---
    double s1 = 0.0, s2 = 0.0;
#pragma unroll
    for (int mq = 0; mq < 4; ++mq) {
        int m = j + mq * 256;
        int k = m >> 7;
        int t = ind[k] + (m & (PAT_LEN - 1)) - HALF_PAT;
        t = min(max(t, 0), T_DIM - 1);
        s1 += rs[t];
        s2 += rq[t];
    }
#pragma unroll
    for (int off = 32; off >= 1; off >>= 1) {
        s1 += __shfl_down(s1, off, 64);
        s2 += __shfl_down(s2, off, 64);
    }
    if ((j & 63) == 0) { w1[j >> 6] = s1; w2[j >> 6] = s2; }
    __syncthreads();
    if (j == 0) {
        double S1 = (w1[0] + w1[1]) + (w1[2] + w1[3]);
        double S2 = (w2[0] + w2[1]) + (w2[2] + w2[3]);
        const double N = (double)(NUM_PAT * PAT_LEN) * (double)D_DIM;
        double mean = S1 / N;
        double var  = (S2 - S1 * S1 / N) / (N - 1.0);
        if (var < 0.0) var = 0.0;
        float stdf = (float)sqrt(var);
        params[b].mean = (float)mean;
        params[b].inv  = 1.0f / (stdf + 1e-8f);
#pragma unroll
        for (int k = 0; k < NUM_PAT; ++k) {
            params[b].lo[k] = max(0, ind[k] - HALF_PAT);
            params[b].hi[k] = min(T_DIM - 1, ind[k] + HALF_PAT - 1);
        }
    }
}

// ---------------------------------------------------------------------------
// Kernel 3: elementwise apply for one chunk. 4 rows per 256-thread block,
// one wave per row (mask & params wave-uniform -> zero divergence). The
// chunk's 128 MB of x was read by row_reduce two dispatches ago with only
// ~1 MB of intervening traffic -> L3-resident -> this kernel is HBM-write-
// bound. Non-temporal stores keep `out` from evicting the chunk's x in L3.
// ---------------------------------------------------------------------------
__global__ __launch_bounds__(256) void apply_kernel(
        const float* __restrict__ x,
        const float* __restrict__ gamma,
        const float* __restrict__ beta,
        const BatchParams* __restrict__ params,
        float* __restrict__ out,
        int base_row) {
    int row  = base_row + (int)(blockIdx.x << 2) + (int)(threadIdx.x >> 6);
    int lane = threadIdx.x & 63;
    int b = row >> 12;                                  // T = 4096 rows/batch
    int t = row & (T_DIM - 1);
    const BatchParams* P = params + b;
    bool covered = false;
#pragma unroll
    for (int k = 0; k < NUM_PAT; ++k)
        covered |= (t >= P->lo[k] && t <= P->hi[k]);
    float mask = covered ? (float)0.8807970779778823 : (float)0.04742587317756678;
    float mean = P->mean;
    float inv  = P->inv;

    size_t base = (size_t)row * D_DIM;
    const float4* xp = (const float4*)(x + base);
    float4*       op = (float4*)(out + base);
    const float4* gp = (const float4*)gamma;
    const float4* bp = (const float4*)beta;

    float4 xv[4], g[4], bt[4];
#pragma unroll
    for (int q = 0; q < 4; ++q) {
        int c4 = lane + q * 64;
        xv[q] = xp[c4];
        g[q]  = gp[c4];
        bt[q] = bp[c4];
    }
#pragma unroll
    for (int q = 0; q < 4; ++q) {
        f4 o;
        o.x = (g[q].x * ((xv[q].x - mean) * inv) + bt[q].x) * mask;
        o.y = (g[q].y * ((xv[q].y - mean) * inv) + bt[q].y) * mask;
        o.z = (g[q].z * ((xv[q].z - mean) * inv) + bt[q].z) * mask;
        o.w = (g[q].w * ((xv[q].w - mean) * inv) + bt[q].w) * mask;
        __builtin_nontemporal_store(o, (f4*)(op + lane + q * 64));
    }
}

// ---------------------------------------------------------------------------
extern "C" void kernel_launch(void* const* d_in, const int* in_sizes, int n_in,
                              void* d_out, int out_size, void* d_ws, size_t ws_size,
                              hipStream_t stream) {
    const float* x     = (const float*)d_in[0];
    const float* gamma = (const float*)d_in[1];
    const float* beta  = (const float*)d_in[2];
    float* out = (float*)d_out;

    int total = in_sizes[0];
    int B = total / (T_DIM * D_DIM);
    int nrows = B * T_DIM;

    double* rowsum   = (double*)d_ws;
    double* rowsumsq = rowsum + nrows;
    BatchParams* params =
        (BatchParams*)((char*)d_ws + 2 * (size_t)nrows * sizeof(double));

    for (int b0 = 0; b0 < B; b0 += CHUNK_B) {
        int nb = (B - b0 < CHUNK_B) ? (B - b0) : CHUNK_B;
        int rows = nb * T_DIM;
        int base_row = b0 * T_DIM;
        row_reduce_kernel<<<rows / 4, 256, 0, stream>>>(
            x, rowsum, rowsumsq, base_row);
        select_kernel<<<nb, 256, 0, stream>>>(rowsum, rowsumsq, params, b0);
        apply_kernel<<<rows / 4, 256, 0, stream>>>(
            x, gamma, beta, params, out, base_row);
    }
}

// Round 4
// 513.577 us; speedup vs baseline: 4.6982x; 1.0016x over previous
//
#include <hip/hip_runtime.h>
#include <math.h>

#define T_DIM 4096
#define D_DIM 1024
#define NUM_PAT 8
#define PAT_LEN 128
#define HALF_PAT 64

typedef __attribute__((ext_vector_type(4))) float f4;

struct BatchParams {
    float mean;
    float inv;
    int lo[NUM_PAT];
    int hi[NUM_PAT];
    int pad[14];   // pad to 128 B
};

// ---------------------------------------------------------------------------
// (v,i) total order matching jax.lax.top_k: value descending, ties -> lower
// index wins. All elements have distinct i, so this is a strict total order.
// ---------------------------------------------------------------------------
__device__ __forceinline__ bool better(float va, int ia, float vb, int ib) {
    return (va > vb) || (va == vb && ia < ib);
}

// Merge two descending-sorted 8-lists (a, b) -> a holds top-8 of the union.
// Bitonic half-cleaner + dist 4/2/1 clean; all indices compile-time.
__device__ __forceinline__ void merge8(float* av, int* ai,
                                       const float* bv, const int* bi) {
    float mv[8]; int mi[8];
#pragma unroll
    for (int q = 0; q < 8; ++q) {
        if (better(av[q], ai[q], bv[7 - q], bi[7 - q])) {
            mv[q] = av[q]; mi[q] = ai[q];
        } else {
            mv[q] = bv[7 - q]; mi[q] = bi[7 - q];
        }
    }
#define CE(a_, b_) { if (better(mv[b_], mi[b_], mv[a_], mi[a_])) { \
            float tv = mv[a_]; mv[a_] = mv[b_]; mv[b_] = tv;       \
            int   ti = mi[a_]; mi[a_] = mi[b_]; mi[b_] = ti; } }
    CE(0, 4) CE(1, 5) CE(2, 6) CE(3, 7)   // dist 4
    CE(0, 2) CE(1, 3) CE(4, 6) CE(5, 7)   // dist 2
    CE(0, 1) CE(2, 3) CE(4, 5) CE(6, 7)   // dist 1
#undef CE
#pragma unroll
    for (int q = 0; q < 8; ++q) { av[q] = mv[q]; ai[q] = mi[q]; }
}

// ---------------------------------------------------------------------------
// Kernel 1: per-row sum and sum-of-squares in fp64. One wave per 2 rows of
// D=1024 floats (8 independent float4 loads in flight per lane); 4 waves =
// 8 rows per 256-thread block. Memory-bound (reads x once, 256 MB).
// ---------------------------------------------------------------------------
__global__ __launch_bounds__(256) void row_reduce_kernel(
        const float* __restrict__ x,
        double* __restrict__ rowsum,
        double* __restrict__ rowsumsq) {
    int wavepair = (int)((blockIdx.x << 2) + (threadIdx.x >> 6));  // 2 rows each
    int lane = threadIdx.x & 63;
    int rowA = wavepair << 1;
    const float4* xa = (const float4*)(x + (size_t)rowA * D_DIM);
    float4 v[8];
#pragma unroll
    for (int q = 0; q < 8; ++q) v[q] = xa[lane + q * 64];  // rows A(0..3) B(4..7)
    double s1a = 0.0, s2a = 0.0, s1b = 0.0, s2b = 0.0;
#pragma unroll
    for (int q = 0; q < 4; ++q) {
        double a = (double)v[q].x, b = (double)v[q].y;
        double c = (double)v[q].z, d = (double)v[q].w;
        s1a += (a + b) + (c + d);
        s2a += (a * a + b * b) + (c * c + d * d);
    }
#pragma unroll
    for (int q = 4; q < 8; ++q) {
        double a = (double)v[q].x, b = (double)v[q].y;
        double c = (double)v[q].z, d = (double)v[q].w;
        s1b += (a + b) + (c + d);
        s2b += (a * a + b * b) + (c * c + d * d);
    }
#pragma unroll
    for (int off = 32; off >= 1; off >>= 1) {
        s1a += __shfl_down(s1a, off, 64);
        s2a += __shfl_down(s2a, off, 64);
        s1b += __shfl_down(s1b, off, 64);
        s2b += __shfl_down(s2b, off, 64);
    }
    if (lane == 0) {
        rowsum[rowA]       = s1a;
        rowsumsq[rowA]     = s2a;
        rowsum[rowA + 1]   = s1b;
        rowsumsq[rowA + 1] = s2b;
    }
}

// ---------------------------------------------------------------------------
// Kernel 2: one 256-thread block per batch.
//  - xt (fp32) from rowsum; peak mask (3-window local max, -inf borders)
//  - top-8: per-thread sorted top-8 over 16 stride-256 candidates, then
//    barrier-free in-wave __shfl_xor butterfly merge (6 levels; every lane
//    converges to its wave's top-8), then a single LDS merge of the 4 wave
//    lists. Tie-break identical to jax.lax.top_k. 3 barriers total.
//  - window-gathered mean / unbiased std via rowsum/rowsumsq (fp64),
//    wave-shuffle reduction.
// ---------------------------------------------------------------------------
__global__ __launch_bounds__(256) void select_kernel(
        const double* __restrict__ rowsum,
        const double* __restrict__ rowsumsq,
        BatchParams* __restrict__ params) {
    int b = blockIdx.x;
    int j = threadIdx.x;
    int lane = j & 63;
    int w = j >> 6;
    __shared__ float xs[T_DIM];
    __shared__ float sv[4 * 8];
    __shared__ int   si[4 * 8];
    __shared__ int   ind[NUM_PAT];
    __shared__ double w1[4], w2[4];

    const double* rs = rowsum   + (size_t)b * T_DIM;
    const double* rq = rowsumsq + (size_t)b * T_DIM;

    for (int t = j; t < T_DIM; t += 256) xs[t] = (float)rs[t];
    __syncthreads();

    // --- per-thread sorted top-8 over 16 stride-256 candidates ------------
    float lv[8]; int li[8];
#pragma unroll
    for (int q = 0; q < 8; ++q) { lv[q] = -INFINITY; li[q] = 0x7fffffff; }
#pragma unroll
    for (int q = 0; q < 16; ++q) {
        int t = j + q * 256;
        float c = xs[t];
        float l = (t > 0)         ? xs[t - 1] : -INFINITY;
        float r = (t < T_DIM - 1) ? xs[t + 1] : -INFINITY;
        float v = (c >= l && c >= r) ? c : 0.0f;   // local peak else 0
        if (better(v, t, lv[7], li[7])) {
            lv[7] = v; li[7] = t;
#pragma unroll
            for (int p = 7; p > 0; --p) {
                if (better(lv[p], li[p], lv[p - 1], li[p - 1])) {
                    float tv = lv[p]; lv[p] = lv[p - 1]; lv[p - 1] = tv;
                    int   ti = li[p]; li[p] = li[p - 1]; li[p - 1] = ti;
                }
            }
        }
    }

    // --- in-wave butterfly merge (no barriers): 64 lists -> 1 per wave ----
#pragma unroll
    for (int m = 1; m <= 32; m <<= 1) {
        float ov[8]; int oi[8];
#pragma unroll
        for (int q = 0; q < 8; ++q) {
            ov[q] = __shfl_xor(lv[q], m, 64);
            oi[q] = __shfl_xor(li[q], m, 64);
        }
        merge8(lv, li, ov, oi);
    }
    if (lane == 0) {
#pragma unroll
        for (int q = 0; q < 8; ++q) { sv[(w << 3) + q] = lv[q]; si[(w << 3) + q] = li[q]; }
    }
    __syncthreads();

    // --- warp 0 merges the 4 wave lists (redundant across its lanes) ------
    if (w == 0) {
        float av[8], bv2[8], cv[8];
        int   ai[8], bi2[8], ci[8];
#pragma unroll
        for (int q = 0; q < 8; ++q) {
            av[q]  = sv[q];      ai[q]  = si[q];
            bv2[q] = sv[8 + q];  bi2[q] = si[8 + q];
        }
        merge8(av, ai, bv2, bi2);
#pragma unroll
        for (int q = 0; q < 8; ++q) {
            bv2[q] = sv[16 + q]; bi2[q] = si[16 + q];
            cv[q]  = sv[24 + q]; ci[q]  = si[24 + q];
        }
        merge8(bv2, bi2, cv, ci);
        merge8(av, ai, bv2, bi2);
        if (j == 0) {
#pragma unroll
            for (int k = 0; k < NUM_PAT; ++k) ind[k] = ai[k];
        }
    }
    __syncthreads();

    // --- gather-window sums over M = 8*128 (clipped, possibly dup) rows ---
    double s1 = 0.0, s2 = 0.0;
#pragma unroll
    for (int mq = 0; mq < 4; ++mq) {
        int m = j + mq * 256;
        int k = m >> 7;
        int t = ind[k] + (m & (PAT_LEN - 1)) - HALF_PAT;
        t = min(max(t, 0), T_DIM - 1);
        s1 += rs[t];
        s2 += rq[t];
    }
#pragma unroll
    for (int off = 32; off >= 1; off >>= 1) {
        s1 += __shfl_down(s1, off, 64);
        s2 += __shfl_down(s2, off, 64);
    }
    if (lane == 0) { w1[w] = s1; w2[w] = s2; }
    __syncthreads();
    if (j == 0) {
        double S1 = (w1[0] + w1[1]) + (w1[2] + w1[3]);
        double S2 = (w2[0] + w2[1]) + (w2[2] + w2[3]);
        const double N = (double)(NUM_PAT * PAT_LEN) * (double)D_DIM;
        double mean = S1 / N;
        double var  = (S2 - S1 * S1 / N) / (N - 1.0);
        if (var < 0.0) var = 0.0;
        float stdf = (float)sqrt(var);
        params[b].mean = (float)mean;
        params[b].inv  = 1.0f / (stdf + 1e-8f);
#pragma unroll
        for (int k = 0; k < NUM_PAT; ++k) {
            params[b].lo[k] = max(0, ind[k] - HALF_PAT);
            params[b].hi[k] = min(T_DIM - 1, ind[k] + HALF_PAT - 1);
        }
    }
}

// ---------------------------------------------------------------------------
// Kernel 3: elementwise apply. 4 rows per 256-thread block, one wave per row
// (mask & params wave-uniform -> zero divergence). Plain (caching) stores:
// NT's only purpose was protecting x's L3 residency, which R1/R3 proved
// worthless (L3 service BW ~= HBM BW on this part); plain stores keep L2
// write-combining in play.
// ---------------------------------------------------------------------------
__global__ __launch_bounds__(256) void apply_kernel(
        const float* __restrict__ x,
        const float* __restrict__ gamma,
        const float* __restrict__ beta,
        const BatchParams* __restrict__ params,
        float* __restrict__ out) {
    int row  = (int)(blockIdx.x << 2) + (int)(threadIdx.x >> 6);
    int lane = threadIdx.x & 63;
    int b = row >> 12;                                  // T = 4096 rows/batch
    int t = row & (T_DIM - 1);
    const BatchParams* P = params + b;
    bool covered = false;
#pragma unroll
    for (int k = 0; k < NUM_PAT; ++k)
        covered |= (t >= P->lo[k] && t <= P->hi[k]);
    float mask = covered ? (float)0.8807970779778823 : (float)0.04742587317756678;
    float mean = P->mean;
    float inv  = P->inv;

    size_t base = (size_t)row * D_DIM;
    const float4* xp = (const float4*)(x + base);
    float4*       op = (float4*)(out + base);
    const float4* gp = (const float4*)gamma;
    const float4* bp = (const float4*)beta;

    float4 xv[4], g[4], bt[4];
#pragma unroll
    for (int q = 0; q < 4; ++q) {
        int c4 = lane + q * 64;
        xv[q] = xp[c4];
        g[q]  = gp[c4];
        bt[q] = bp[c4];
    }
#pragma unroll
    for (int q = 0; q < 4; ++q) {
        f4 o;
        o.x = (g[q].x * ((xv[q].x - mean) * inv) + bt[q].x) * mask;
        o.y = (g[q].y * ((xv[q].y - mean) * inv) + bt[q].y) * mask;
        o.z = (g[q].z * ((xv[q].z - mean) * inv) + bt[q].z) * mask;
        o.w = (g[q].w * ((xv[q].w - mean) * inv) + bt[q].w) * mask;
        *(f4*)(op + lane + q * 64) = o;
    }
}

// ---------------------------------------------------------------------------
extern "C" void kernel_launch(void* const* d_in, const int* in_sizes, int n_in,
                              void* d_out, int out_size, void* d_ws, size_t ws_size,
                              hipStream_t stream) {
    const float* x     = (const float*)d_in[0];
    const float* gamma = (const float*)d_in[1];
    const float* beta  = (const float*)d_in[2];
    float* out = (float*)d_out;

    int total = in_sizes[0];
    int B = total / (T_DIM * D_DIM);
    int nrows = B * T_DIM;

    double* rowsum   = (double*)d_ws;
    double* rowsumsq = rowsum + nrows;
    BatchParams* params =
        (BatchParams*)((char*)d_ws + 2 * (size_t)nrows * sizeof(double));

    row_reduce_kernel<<<nrows / 8, 256, 0, stream>>>(x, rowsum, rowsumsq);
    select_kernel<<<B, 256, 0, stream>>>(rowsum, rowsumsq, params);
    apply_kernel<<<nrows / 4, 256, 0, stream>>>(x, gamma, beta, params, out);
}

// Round 5
// 489.062 us; speedup vs baseline: 4.9337x; 1.0501x over previous
//
#include <hip/hip_runtime.h>
#include <math.h>

#define T_DIM 4096
#define D_DIM 1024
#define NUM_PAT 8
#define PAT_LEN 128
#define HALF_PAT 64

typedef __attribute__((ext_vector_type(4))) float f4;

struct BatchParams {
    float mean;
    float inv;
    int lo[NUM_PAT];
    int hi[NUM_PAT];
    int pad[14];   // pad to 128 B
};

// ---------------------------------------------------------------------------
// (v,i) total order matching jax.lax.top_k: value descending, ties -> lower
// index wins. All elements have distinct i, so this is a strict total order.
// ---------------------------------------------------------------------------
__device__ __forceinline__ bool better(float va, int ia, float vb, int ib) {
    return (va > vb) || (va == vb && ia < ib);
}

// Merge two descending-sorted 8-lists (a, b) -> a holds top-8 of the union.
// Bitonic half-cleaner + dist 4/2/1 clean; all indices compile-time.
__device__ __forceinline__ void merge8(float* av, int* ai,
                                       const float* bv, const int* bi) {
    float mv[8]; int mi[8];
#pragma unroll
    for (int q = 0; q < 8; ++q) {
        if (better(av[q], ai[q], bv[7 - q], bi[7 - q])) {
            mv[q] = av[q]; mi[q] = ai[q];
        } else {
            mv[q] = bv[7 - q]; mi[q] = bi[7 - q];
        }
    }
#define CE(a_, b_) { if (better(mv[b_], mi[b_], mv[a_], mi[a_])) { \
            float tv = mv[a_]; mv[a_] = mv[b_]; mv[b_] = tv;       \
            int   ti = mi[a_]; mi[a_] = mi[b_]; mi[b_] = ti; } }
    CE(0, 4) CE(1, 5) CE(2, 6) CE(3, 7)   // dist 4
    CE(0, 2) CE(1, 3) CE(4, 6) CE(5, 7)   // dist 2
    CE(0, 1) CE(2, 3) CE(4, 5) CE(6, 7)   // dist 1
#undef CE
#pragma unroll
    for (int q = 0; q < 8; ++q) { av[q] = mv[q]; ai[q] = mi[q]; }
}

// ---------------------------------------------------------------------------
// Kernel 1: per-row sum and sum-of-squares in fp64. One wave (64 lanes) per
// row of D=1024 floats; 4 waves per 256-thread block. Memory-bound (reads x,
// 256 MB). [R0/R1-proven config: 486/488 us total. R4's 2-row/wave variant
// was part of a +25 us regression -- reverted.]
// ---------------------------------------------------------------------------
__global__ __launch_bounds__(256) void row_reduce_kernel(
        const float* __restrict__ x,
        double* __restrict__ rowsum,
        double* __restrict__ rowsumsq,
        int nrows) {
    int wave = (int)((blockIdx.x * blockDim.x + threadIdx.x) >> 6);
    int lane = threadIdx.x & 63;
    if (wave >= nrows) return;
    const float4* xp = (const float4*)(x + (size_t)wave * D_DIM);
    float4 v[4];
#pragma unroll
    for (int q = 0; q < 4; ++q) v[q] = xp[lane + q * 64];   // 4 indep loads in flight
    double s1 = 0.0, s2 = 0.0;
#pragma unroll
    for (int q = 0; q < 4; ++q) {
        double a = (double)v[q].x, b = (double)v[q].y;
        double c = (double)v[q].z, d = (double)v[q].w;
        s1 += (a + b) + (c + d);
        s2 += (a * a + b * b) + (c * c + d * d);
    }
#pragma unroll
    for (int off = 32; off >= 1; off >>= 1) {
        s1 += __shfl_down(s1, off, 64);
        s2 += __shfl_down(s2, off, 64);
    }
    if (lane == 0) {
        rowsum[wave] = s1;
        rowsumsq[wave] = s2;
    }
}

// ---------------------------------------------------------------------------
// Kernel 2: one 256-thread block per batch.
//  - xt (fp32) from rowsum; peak mask (3-window local max, -inf borders)
//  - top-8: per-thread sorted top-8 over 16 stride-256 candidates, then
//    barrier-free in-wave __shfl_xor butterfly merge (6 levels; every lane
//    converges to its wave's top-8), then a single LDS merge of the 4 wave
//    lists. Tie-break identical to jax.lax.top_k. 3 barriers total.
//  - window-gathered mean / unbiased std via rowsum/rowsumsq (fp64),
//    wave-shuffle reduction.
// ---------------------------------------------------------------------------
__global__ __launch_bounds__(256) void select_kernel(
        const double* __restrict__ rowsum,
        const double* __restrict__ rowsumsq,
        BatchParams* __restrict__ params) {
    int b = blockIdx.x;
    int j = threadIdx.x;
    int lane = j & 63;
    int w = j >> 6;
    __shared__ float xs[T_DIM];
    __shared__ float sv[4 * 8];
    __shared__ int   si[4 * 8];
    __shared__ int   ind[NUM_PAT];
    __shared__ double w1[4], w2[4];

    const double* rs = rowsum   + (size_t)b * T_DIM;
    const double* rq = rowsumsq + (size_t)b * T_DIM;

    for (int t = j; t < T_DIM; t += 256) xs[t] = (float)rs[t];
    __syncthreads();

    // --- per-thread sorted top-8 over 16 stride-256 candidates ------------
    float lv[8]; int li[8];
#pragma unroll
    for (int q = 0; q < 8; ++q) { lv[q] = -INFINITY; li[q] = 0x7fffffff; }
#pragma unroll
    for (int q = 0; q < 16; ++q) {
        int t = j + q * 256;
        float c = xs[t];
        float l = (t > 0)         ? xs[t - 1] : -INFINITY;
        float r = (t < T_DIM - 1) ? xs[t + 1] : -INFINITY;
        float v = (c >= l && c >= r) ? c : 0.0f;   // local peak else 0
        if (better(v, t, lv[7], li[7])) {
            lv[7] = v; li[7] = t;
#pragma unroll
            for (int p = 7; p > 0; --p) {
                if (better(lv[p], li[p], lv[p - 1], li[p - 1])) {
                    float tv = lv[p]; lv[p] = lv[p - 1]; lv[p - 1] = tv;
                    int   ti = li[p]; li[p] = li[p - 1]; li[p - 1] = ti;
                }
            }
        }
    }

    // --- in-wave butterfly merge (no barriers): 64 lists -> 1 per wave ----
#pragma unroll
    for (int m = 1; m <= 32; m <<= 1) {
        float ov[8]; int oi[8];
#pragma unroll
        for (int q = 0; q < 8; ++q) {
            ov[q] = __shfl_xor(lv[q], m, 64);
            oi[q] = __shfl_xor(li[q], m, 64);
        }
        merge8(lv, li, ov, oi);
    }
    if (lane == 0) {
#pragma unroll
        for (int q = 0; q < 8; ++q) { sv[(w << 3) + q] = lv[q]; si[(w << 3) + q] = li[q]; }
    }
    __syncthreads();

    // --- warp 0 merges the 4 wave lists (redundant across its lanes) ------
    if (w == 0) {
        float av[8], bv2[8], cv[8];
        int   ai[8], bi2[8], ci[8];
#pragma unroll
        for (int q = 0; q < 8; ++q) {
            av[q]  = sv[q];      ai[q]  = si[q];
            bv2[q] = sv[8 + q];  bi2[q] = si[8 + q];
        }
        merge8(av, ai, bv2, bi2);
#pragma unroll
        for (int q = 0; q < 8; ++q) {
            bv2[q] = sv[16 + q]; bi2[q] = si[16 + q];
            cv[q]  = sv[24 + q]; ci[q]  = si[24 + q];
        }
        merge8(bv2, bi2, cv, ci);
        merge8(av, ai, bv2, bi2);
        if (j == 0) {
#pragma unroll
            for (int k = 0; k < NUM_PAT; ++k) ind[k] = ai[k];
        }
    }
    __syncthreads();

    // --- gather-window sums over M = 8*128 (clipped, possibly dup) rows ---
    double s1 = 0.0, s2 = 0.0;
#pragma unroll
    for (int mq = 0; mq < 4; ++mq) {
        int m = j + mq * 256;
        int k = m >> 7;
        int t = ind[k] + (m & (PAT_LEN - 1)) - HALF_PAT;
        t = min(max(t, 0), T_DIM - 1);
        s1 += rs[t];
        s2 += rq[t];
    }
#pragma unroll
    for (int off = 32; off >= 1; off >>= 1) {
        s1 += __shfl_down(s1, off, 64);
        s2 += __shfl_down(s2, off, 64);
    }
    if (lane == 0) { w1[w] = s1; w2[w] = s2; }
    __syncthreads();
    if (j == 0) {
        double S1 = (w1[0] + w1[1]) + (w1[2] + w1[3]);
        double S2 = (w2[0] + w2[1]) + (w2[2] + w2[3]);
        const double N = (double)(NUM_PAT * PAT_LEN) * (double)D_DIM;
        double mean = S1 / N;
        double var  = (S2 - S1 * S1 / N) / (N - 1.0);
        if (var < 0.0) var = 0.0;
        float stdf = (float)sqrt(var);
        params[b].mean = (float)mean;
        params[b].inv  = 1.0f / (stdf + 1e-8f);
#pragma unroll
        for (int k = 0; k < NUM_PAT; ++k) {
            params[b].lo[k] = max(0, ind[k] - HALF_PAT);
            params[b].hi[k] = min(T_DIM - 1, ind[k] + HALF_PAT - 1);
        }
    }
}

// ---------------------------------------------------------------------------
// Kernel 3: elementwise apply. 4 rows per 256-thread block, one wave per row
// (mask & params wave-uniform -> zero divergence). NON-TEMPORAL stores are
// empirically worth ~25 us (R4: plain stores regressed 488 -> 513.6): they
// keep the 256 MB `out` write stream from allocating/dirtying L2/L3 and
// interleaving writebacks with x's read stream. [R0/R1-proven kernel.]
// ---------------------------------------------------------------------------
__global__ __launch_bounds__(256) void apply_kernel(
        const float* __restrict__ x,
        const float* __restrict__ gamma,
        const float* __restrict__ beta,
        const BatchParams* __restrict__ params,
        float* __restrict__ out) {
    int row  = (int)(blockIdx.x << 2) + (int)(threadIdx.x >> 6);  // 4 rows/block
    int lane = threadIdx.x & 63;
    int b = row >> 12;                                  // T = 4096 rows/batch
    int t = row & (T_DIM - 1);
    const BatchParams* P = params + b;
    bool covered = false;
#pragma unroll
    for (int k = 0; k < NUM_PAT; ++k)
        covered |= (t >= P->lo[k] && t <= P->hi[k]);
    float mask = covered ? (float)0.8807970779778823 : (float)0.04742587317756678;
    float mean = P->mean;
    float inv  = P->inv;

    size_t base = (size_t)row * D_DIM;
    const float4* xp = (const float4*)(x + base);
    float4*       op = (float4*)(out + base);
    const float4* gp = (const float4*)gamma;
    const float4* bp = (const float4*)beta;

    float4 xv[4], g[4], bt[4];
#pragma unroll
    for (int q = 0; q < 4; ++q) {
        int c4 = lane + q * 64;
        xv[q] = xp[c4];
        g[q]  = gp[c4];
        bt[q] = bp[c4];
    }
#pragma unroll
    for (int q = 0; q < 4; ++q) {
        f4 o;
        o.x = (g[q].x * ((xv[q].x - mean) * inv) + bt[q].x) * mask;
        o.y = (g[q].y * ((xv[q].y - mean) * inv) + bt[q].y) * mask;
        o.z = (g[q].z * ((xv[q].z - mean) * inv) + bt[q].z) * mask;
        o.w = (g[q].w * ((xv[q].w - mean) * inv) + bt[q].w) * mask;
        __builtin_nontemporal_store(o, (f4*)(op + lane + q * 64));
    }
}

// ---------------------------------------------------------------------------
extern "C" void kernel_launch(void* const* d_in, const int* in_sizes, int n_in,
                              void* d_out, int out_size, void* d_ws, size_t ws_size,
                              hipStream_t stream) {
    const float* x     = (const float*)d_in[0];
    const float* gamma = (const float*)d_in[1];
    const float* beta  = (const float*)d_in[2];
    float* out = (float*)d_out;

    int total = in_sizes[0];
    int B = total / (T_DIM * D_DIM);
    int nrows = B * T_DIM;

    double* rowsum   = (double*)d_ws;
    double* rowsumsq = rowsum + nrows;
    BatchParams* params =
        (BatchParams*)((char*)d_ws + 2 * (size_t)nrows * sizeof(double));

    row_reduce_kernel<<<(nrows + 3) / 4, 256, 0, stream>>>(x, rowsum, rowsumsq, nrows);
    select_kernel<<<B, 256, 0, stream>>>(rowsum, rowsumsq, params);
    apply_kernel<<<nrows / 4, 256, 0, stream>>>(x, gamma, beta, params, out);
}